// Round 9
// baseline (139.841 us; speedup 1.0000x reference)
//
#include <hip/hip_runtime.h>
#include <stdint.h>

#define N_B 4
#define S_LEN 2048
#define N_H 8
#define E_DIM 512

typedef __attribute__((ext_vector_type(8))) short bf16x8;
typedef __attribute__((ext_vector_type(4))) float f32x4;
typedef __attribute__((ext_vector_type(4))) unsigned int u32x4;
typedef __attribute__((ext_vector_type(2))) unsigned int u32x2;
typedef __attribute__((ext_vector_type(4))) unsigned short u16x4;
typedef __attribute__((ext_vector_type(8))) unsigned short u16x8;

#define MFMA16(a, b, c) __builtin_amdgcn_mfma_f32_16x16x32_bf16((a), (b), (c), 0, 0, 0)

__device__ __forceinline__ unsigned short f2bf(float f) {
    union { float f; unsigned int u; } v; v.f = f;
    unsigned int r = v.u + 0x7fffu + ((v.u >> 16) & 1u);
    return (unsigned short)(r >> 16);
}

// pack two f32 -> two bf16 (round-half-up) in one u32 via v_perm
__device__ __forceinline__ unsigned int pack2bf(float lo, float hi) {
    union { float f; unsigned int u; } a, b; a.f = lo; b.f = hi;
    return __builtin_amdgcn_perm(b.u + 0x8000u, a.u + 0x8000u, 0x07060302u);
}

__device__ __forceinline__ float fexp2(float x) {
#if __has_builtin(__builtin_amdgcn_exp2f)
    return __builtin_amdgcn_exp2f(x);
#else
    return exp2f(x);
#endif
}

// ---------------------------------------------------------------------------
// In-register quad redistribution (lane^32 and lane^16 swaps at fixed lq).
// ---------------------------------------------------------------------------
#if __has_builtin(__builtin_amdgcn_permlane32_swap) && __has_builtin(__builtin_amdgcn_permlane16_swap)
#define HAVE_PERMLANE_SWAP 1
#endif

__device__ __forceinline__ void pl32(unsigned int& x, unsigned int& y) {
#ifdef HAVE_PERMLANE_SWAP
    auto r = __builtin_amdgcn_permlane32_swap(x, y, false, false);
    x = (unsigned int)r[0]; y = (unsigned int)r[1];
#else
    const int idx = (((int)threadIdx.x & 63) ^ 32) << 2;
    unsigned int xs = (unsigned int)__builtin_amdgcn_ds_bpermute(idx, (int)x);
    unsigned int ys = (unsigned int)__builtin_amdgcn_ds_bpermute(idx, (int)y);
    const bool lo = (threadIdx.x & 32) == 0;
    unsigned int nx = lo ? x : ys;
    unsigned int ny = lo ? xs : y;
    x = nx; y = ny;
#endif
}

__device__ __forceinline__ void pl16(unsigned int& x, unsigned int& y) {
#ifdef HAVE_PERMLANE_SWAP
    auto r = __builtin_amdgcn_permlane16_swap(x, y, false, false);
    x = (unsigned int)r[0]; y = (unsigned int)r[1];
#else
    unsigned int zs = (unsigned int)__builtin_amdgcn_ds_swizzle((int)y, 0x401F); // y[lane^16]
    unsigned int ws = (unsigned int)__builtin_amdgcn_ds_swizzle((int)x, 0x401F); // x[lane^16]
    const bool evenq = (threadIdx.x & 16) == 0;
    unsigned int nx = evenq ? x : zs;
    unsigned int ny = evenq ? ws : y;
    x = nx; y = ny;
#endif
}

// Q pre-scale: 1/sqrt(64) * log2(e)
#define Q_SCALE 0.18033688f

// ---------------------------------------------------------------------------
// Kernel 1: proj = cos(x+theta); Q,K row-major [BH][S][64] bf16 (Q*Q_SCALE);
//           Vt [BH][64][S] bf16.  grid = 256 chunks x 3 mats = 768 blocks.
// (R1/R3/R8-verified, unchanged.)
// ---------------------------------------------------------------------------
__global__ __launch_bounds__(256) void qkv_kernel(
    const float* __restrict__ x, const float* __restrict__ theta,
    const float* __restrict__ Wq, const float* __restrict__ Wk,
    const float* __restrict__ Wv,
    unsigned short* __restrict__ Q, unsigned short* __restrict__ K,
    unsigned short* __restrict__ Vt)
{
    __shared__ float proj[32][8];
    const int tid = threadIdx.x;
    const int mat = blockIdx.x % 3;
    const int chunk = blockIdx.x / 3;
    const int row0 = chunk * 32;
    const int b = row0 >> 11;
    const int s_in_b = row0 & (S_LEN - 1);

    proj[tid >> 3][tid & 7] = cosf(x[row0 * 8 + tid] + theta[tid & 7]);
    __syncthreads();

    if (mat < 2) {
        const float* W = (mat == 0) ? Wq : Wk;
        const float scale = (mat == 0) ? Q_SCALE : 1.0f;
        unsigned short* outp = (mat == 0) ? Q : K;
        const int eg = (tid & 127) * 4;      // 4 consecutive e-columns
        const int sg = (tid >> 7) * 16;      // 16 s-rows
        float w[4][8];
        #pragma unroll
        for (int e = 0; e < 4; ++e)
            #pragma unroll
            for (int n = 0; n < 8; ++n)
                w[e][n] = W[(eg + e) * 8 + n] * scale;
        const int h = eg >> 6, d0 = eg & 63;
        unsigned short* p0 = outp + ((size_t)(b * N_H + h) * S_LEN + s_in_b + sg) * 64 + d0;
        #pragma unroll 4
        for (int s = 0; s < 16; ++s) {
            f32x4 pa = *(const f32x4*)&proj[sg + s][0];
            f32x4 pc = *(const f32x4*)&proj[sg + s][4];
            u16x4 o;
            #pragma unroll
            for (int e = 0; e < 4; ++e) {
                float a = 0.f;
                #pragma unroll
                for (int n = 0; n < 4; ++n)
                    a += pa[n] * w[e][n] + pc[n] * w[e][n + 4];
                o[e] = f2bf(a);
            }
            *(u16x4*)&p0[s * 64] = o;
        }
    } else {
        // Vt: 4 lanes per e-column; lane handles 8 s-values -> u16x8.
        f32x4 ps[8][2];
        const int sl0 = (tid & 3) * 8;
        #pragma unroll
        for (int k2 = 0; k2 < 8; ++k2) {
            ps[k2][0] = *(const f32x4*)&proj[sl0 + k2][0];
            ps[k2][1] = *(const f32x4*)&proj[sl0 + k2][4];
        }
        const int ecol = tid >> 2;   // 0..63
        for (int pass = 0; pass < 8; ++pass) {
            const int e = pass * 64 + ecol;
            const int h = e >> 6, dd = e & 63;
            float wr[8];
            #pragma unroll
            for (int n = 0; n < 8; ++n) wr[n] = Wv[e * 8 + n];
            u16x8 pk;
            #pragma unroll
            for (int k2 = 0; k2 < 8; ++k2) {
                float acc = 0.f;
                #pragma unroll
                for (int n = 0; n < 4; ++n)
                    acc += ps[k2][0][n] * wr[n] + ps[k2][1][n] * wr[n + 4];
                pk[k2] = f2bf(acc);
            }
            *(u16x8*)&Vt[((size_t)(b * N_H + h) * 64 + dd) * S_LEN + s_in_b + sl0] = pk;
        }
    }
}

// ---------------------------------------------------------------------------
// Kernel 2: flash attention, fixed-max (M=0) softmax, IN-BLOCK K-SPLIT x2.
// R9 changes vs R3/R8 (VALU diet + scheduler bias):
//  (a) row-sums via MFMA-with-ones B-operand: lsacc[mt] accumulates row sums
//      on the 26%-idle matrix pipe; removes 32 v_add/tile from the 45%-busy
//      VALU pipe AND all epilogue shuffles (lsacc rows == oacc rows).
//  (b) s_setprio(1) around MFMA clusters (2 independent blocks/CU at
//      different phases -> T5 precondition holds).
// ---------------------------------------------------------------------------
__global__ __launch_bounds__(512, 4) void flash_kernel(
    const unsigned short* __restrict__ Q, const unsigned short* __restrict__ K,
    const unsigned short* __restrict__ Vt, unsigned short* __restrict__ O)
{
    __shared__ short kt[2][2][64 * 72];   // [group][dbuf][k=64][d=64+pad]
    __shared__ short vt[2][2][64 * 72];   // [group][dbuf][d=64][s=64+pad]

    const int tid = threadIdx.x;               // 0..511
    const int lane = tid & 63, w = tid >> 6;   // w 0..7
    const int g = tid >> 8;                    // k-split group
    const int wq = w & 3;                      // q-wave within group
    const int tg = tid & 255;                  // thread within group
    const int quad = lane >> 4, lq = lane & 15;
    // bijective XCD swizzle (512 blocks, 8 XCDs)
    const int bid = ((int)blockIdx.x & 7) * 64 + ((int)blockIdx.x >> 3);
    const int qt = bid & 15, bh = bid >> 4;
    const int b = bh >> 3, h = bh & 7;

    const unsigned short* Qb = Q + (size_t)bh * S_LEN * 64;
    const unsigned short* Kb = K + (size_t)bh * S_LEN * 64;
    const unsigned short* Vb = Vt + (size_t)bh * 64 * S_LEN;
    const int kbase = g * 1024;                // this group's k-range start

    // all-ones bf16 B-fragment (1.0 = 0x3F80); layout-independent for ones.
    union { unsigned short us[8]; bf16x8 v; } onesu;
    #pragma unroll
    for (int i = 0; i < 8; ++i) onesu.us[i] = 0x3F80;
    const bf16x8 onesf = onesu.v;

    // Q fragments (MFMA B-operand): lane holds Q[q=lq][d=quad*8+j]
    bf16x8 qf[2][2];
    #pragma unroll
    for (int mt = 0; mt < 2; ++mt)
        #pragma unroll
        for (int ks = 0; ks < 2; ++ks)
            qf[mt][ks] = *(const bf16x8*)&Qb[(size_t)(qt * 128 + wq * 32 + mt * 16 + lq) * 64 + ks * 32 + quad * 8];

    f32x4 oacc[2][4];
    #pragma unroll
    for (int mt = 0; mt < 2; ++mt)
        #pragma unroll
        for (int dt = 0; dt < 4; ++dt) oacc[mt][dt] = 0.f;
    f32x4 lsacc[2];
    lsacc[0] = 0.f; lsacc[1] = 0.f;

    // prologue: group tile 0 -> regs -> buf0; group tile 1 -> regs (in flight)
    u32x4 pkr[2], pvr[2];
    #pragma unroll
    for (int i = 0; i < 2; ++i) {
        const int u = tg + (i << 8);
        pkr[i] = *(const u32x4*)&Kb[(size_t)(kbase + (u >> 3)) * 64 + (u & 7) * 8];
        pvr[i] = *(const u32x4*)&Vb[(size_t)(u >> 3) * S_LEN + kbase + (u & 7) * 8];
    }
    #pragma unroll
    for (int i = 0; i < 2; ++i) {
        const int u = tg + (i << 8);
        *(u32x4*)&kt[g][0][(u >> 3) * 72 + (u & 7) * 8] = pkr[i];
        *(u32x4*)&vt[g][0][(u >> 3) * 72 + (u & 7) * 8] = pvr[i];
    }
    #pragma unroll
    for (int i = 0; i < 2; ++i) {
        const int u = tg + (i << 8);
        pkr[i] = *(const u32x4*)&Kb[(size_t)(kbase + 64 + (u >> 3)) * 64 + (u & 7) * 8];
        pvr[i] = *(const u32x4*)&Vb[(size_t)(u >> 3) * S_LEN + kbase + 64 + (u & 7) * 8];
    }
    asm volatile("s_waitcnt lgkmcnt(0)" ::: "memory");
    __builtin_amdgcn_s_barrier();

    for (int kti = 0; kti < 16; ++kti) {
        const int cur = kti & 1, nxt = cur ^ 1;

        // stage group tile kti+1 (regs) -> buf[nxt] (counted vmcnt emitted here)
        #pragma unroll
        for (int i = 0; i < 2; ++i) {
            const int u = tg + (i << 8);
            *(u32x4*)&kt[g][nxt][(u >> 3) * 72 + (u & 7) * 8] = pkr[i];
            *(u32x4*)&vt[g][nxt][(u >> 3) * 72 + (u & 7) * 8] = pvr[i];
        }
        // prefetch group tile kti+2 -> regs (dummy tile 0 past end)
        const int kb2 = kbase + ((kti < 14) ? (kti + 2) * 64 : 0);
        #pragma unroll
        for (int i = 0; i < 2; ++i) {
            const int u = tg + (i << 8);
            pkr[i] = *(const u32x4*)&Kb[(size_t)(kb2 + (u >> 3)) * 64 + (u & 7) * 8];
            pvr[i] = *(const u32x4*)&Vb[(size_t)(u >> 3) * S_LEN + kb2 + (u & 7) * 8];
        }

        const short* ktc = &kt[g][cur][0];
        const short* vtc = &vt[g][cur][0];

        // S^T = K . Q^T : lane (quad,lq) elem r -> S^T[k=mts*16+quad*4+r][q=lq]
        f32x4 sacc[2][4];
        #pragma unroll
        for (int mt = 0; mt < 2; ++mt)
            #pragma unroll
            for (int mts = 0; mts < 4; ++mts) sacc[mt][mts] = 0.f;
        __builtin_amdgcn_s_setprio(1);
        #pragma unroll
        for (int mts = 0; mts < 4; ++mts) {
            #pragma unroll
            for (int ks = 0; ks < 2; ++ks) {
                bf16x8 af = *(const bf16x8*)&ktc[(mts * 16 + lq) * 72 + ks * 32 + quad * 8];
                sacc[0][mts] = MFMA16(af, qf[0][ks], sacc[0][mts]);
                sacc[1][mts] = MFMA16(af, qf[1][ks], sacc[1][mts]);
            }
        }
        __builtin_amdgcn_s_setprio(0);

        // fixed-max softmax + in-register transpose S^T -> PV A-fragments
        unsigned int afr[2][2][4];
        #pragma unroll
        for (int mt = 0; mt < 2; ++mt) {
            unsigned int u_[4][2];
            #pragma unroll
            for (int mts = 0; mts < 4; ++mts) {
                f32x4 p;
                #pragma unroll
                for (int e = 0; e < 4; ++e) p[e] = fexp2(sacc[mt][mts][e]);
                u_[mts][0] = pack2bf(p[0], p[1]);
                u_[mts][1] = pack2bf(p[2], p[3]);
            }
            #pragma unroll
            for (int ks = 0; ks < 2; ++ks) {
                #pragma unroll
                for (int wd = 0; wd < 2; ++wd) {
                    unsigned int a = u_[ks * 2][wd];
                    unsigned int c = u_[ks * 2 + 1][wd];
                    pl32(a, c);
                    pl16(a, c);
                    afr[mt][ks][wd] = a;
                    afr[mt][ks][2 + wd] = c;
                }
            }
        }

        // O += P . V ; row-sums via MFMA with all-ones B (free on matrix pipe)
        __builtin_amdgcn_s_setprio(1);
        #pragma unroll
        for (int ks = 0; ks < 2; ++ks) {
            union { unsigned int u[4]; bf16x8 v; } a0, a1;
            #pragma unroll
            for (int j = 0; j < 4; ++j) { a0.u[j] = afr[0][ks][j]; a1.u[j] = afr[1][ks][j]; }
            lsacc[0] = MFMA16(a0.v, onesf, lsacc[0]);
            lsacc[1] = MFMA16(a1.v, onesf, lsacc[1]);
            #pragma unroll
            for (int dt = 0; dt < 4; ++dt) {
                bf16x8 bf = *(const bf16x8*)&vtc[(dt * 16 + lq) * 72 + ks * 32 + quad * 8];
                oacc[0][dt] = MFMA16(a0.v, bf, oacc[0][dt]);
                oacc[1][dt] = MFMA16(a1.v, bf, oacc[1][dt]);
            }
        }
        __builtin_amdgcn_s_setprio(0);

        asm volatile("s_waitcnt lgkmcnt(0)" ::: "memory");
        __builtin_amdgcn_s_barrier();
    }

    // ---- k-split combine: group 1 -> LDS -> group 0 adds (pure f32) ----
    // stride-36 layout: oacc at [0..31], lsacc[0] at [32..35]; lsacc[1] in exL.
    float* exO = (float*)&kt[0][0][0];   // 9216 floats
    float* exL = (float*)&vt[0][0][0];
    const int fb = wq * 2304 + lane * 36;
    if (g == 1) {
        #pragma unroll
        for (int mt = 0; mt < 2; ++mt)
            #pragma unroll
            for (int dt = 0; dt < 4; ++dt)
                *(f32x4*)&exO[fb + (mt * 4 + dt) * 4] = oacc[mt][dt];
        *(f32x4*)&exO[fb + 32] = lsacc[0];
        *(f32x4*)&exL[(wq * 64 + lane) * 4] = lsacc[1];
    }
    __syncthreads();
    if (g == 0) {
        #pragma unroll
        for (int mt = 0; mt < 2; ++mt)
            #pragma unroll
            for (int dt = 0; dt < 4; ++dt)
                oacc[mt][dt] += *(const f32x4*)&exO[fb + (mt * 4 + dt) * 4];
        lsacc[0] += *(const f32x4*)&exO[fb + 32];
        lsacc[1] += *(const f32x4*)&exL[(wq * 64 + lane) * 4];

        // epilogue: normalize (lsacc rows == oacc rows; no shuffles), store O
        #pragma unroll
        for (int mt = 0; mt < 2; ++mt) {
            #pragma unroll
            for (int r = 0; r < 4; ++r) {
                const float ir = 1.0f / lsacc[mt][r];
                const int row = qt * 128 + wq * 32 + mt * 16 + quad * 4 + r;
                unsigned short* dst = &O[((size_t)b * S_LEN + row) * E_DIM + h * 64];
                #pragma unroll
                for (int dt = 0; dt < 4; ++dt)
                    dst[dt * 16 + lq] = f2bf(oacc[mt][dt][r] * ir);
            }
        }
    }
}

// ---------------------------------------------------------------------------
// Kernel 3: Y[m][f] = sum_e O[m][e]*Wc[f][e].  BM=64 x BN=128, 512 threads,
// grid 512, XCD swizzle. (R8-verified, unchanged.)
// ---------------------------------------------------------------------------
__global__ __launch_bounds__(512) void outproj_kernel(
    const unsigned short* __restrict__ O, const float* __restrict__ Wc,
    float* __restrict__ Y)
{
    __shared__ short at[64 * 72];     // O tile  [m=64][e=64]+pad
    __shared__ short bt[128 * 72];    // Wc tile [f=128][e=64]+pad (bf16)
    const int tid = threadIdx.x;
    const int lane = tid & 63, w = tid >> 6;   // 8 waves
    const int quad = lane >> 4, lq = lane & 15;
    const int rw = w & 3;                      // row-group (16 rows)
    const int fw = w >> 2;                     // f-half (64 cols)
    const int t = ((int)blockIdx.x & 7) * 64 + ((int)blockIdx.x >> 3);
    const int m0 = (t >> 2) * 64;
    const int f0 = (t & 3) * 128;

    f32x4 acc[4];
    #pragma unroll
    for (int nt = 0; nt < 4; ++nt) acc[nt] = 0.f;

    u32x4 pa;
    f32x4 pw[4];
    pa = *(const u32x4*)&O[(size_t)(m0 + (tid >> 3)) * E_DIM + (tid & 7) * 8];
    #pragma unroll
    for (int i = 0; i < 4; ++i) {
        const int u = tid + (i << 9);
        pw[i] = *(const f32x4*)&Wc[(size_t)(f0 + (u >> 4)) * E_DIM + (u & 15) * 4];
    }

    for (int e0 = 0; e0 < E_DIM; e0 += 64) {
        __syncthreads();
        *(u32x4*)&at[(tid >> 3) * 72 + (tid & 7) * 8] = pa;
        #pragma unroll
        for (int i = 0; i < 4; ++i) {
            const int u = tid + (i << 9);
            u16x4 pk = { f2bf(pw[i][0]), f2bf(pw[i][1]), f2bf(pw[i][2]), f2bf(pw[i][3]) };
            *(u16x4*)&bt[(u >> 4) * 72 + (u & 15) * 4] = pk;
        }
        __syncthreads();

        const int e1 = (e0 + 64 < E_DIM) ? e0 + 64 : 0;
        pa = *(const u32x4*)&O[(size_t)(m0 + (tid >> 3)) * E_DIM + e1 + (tid & 7) * 8];
        #pragma unroll
        for (int i = 0; i < 4; ++i) {
            const int u = tid + (i << 9);
            pw[i] = *(const f32x4*)&Wc[(size_t)(f0 + (u >> 4)) * E_DIM + e1 + (u & 15) * 4];
        }

        bf16x8 afk[2];
        #pragma unroll
        for (int ks = 0; ks < 2; ++ks)
            afk[ks] = *(const bf16x8*)&at[(rw * 16 + lq) * 72 + ks * 32 + quad * 8];
        #pragma unroll
        for (int nt = 0; nt < 4; ++nt) {
            #pragma unroll
            for (int ks = 0; ks < 2; ++ks) {
                bf16x8 bf = *(const bf16x8*)&bt[(fw * 64 + nt * 16 + lq) * 72 + ks * 32 + quad * 8];
                acc[nt] = MFMA16(afk[ks], bf, acc[nt]);
            }
        }
    }

    #pragma unroll
    for (int nt = 0; nt < 4; ++nt)
        #pragma unroll
        for (int r = 0; r < 4; ++r)
            Y[(size_t)(m0 + rw * 16 + quad * 4 + r) * E_DIM + f0 + fw * 64 + nt * 16 + lq] = acc[nt][r];
}

// ---------------------------------------------------------------------------
extern "C" void kernel_launch(void* const* d_in, const int* in_sizes, int n_in,
                              void* d_out, int out_size, void* d_ws, size_t ws_size,
                              hipStream_t stream) {
    const float* x     = (const float*)d_in[0];
    const float* theta = (const float*)d_in[1];
    const float* Wq    = (const float*)d_in[2];
    const float* Wk    = (const float*)d_in[3];
    const float* Wv    = (const float*)d_in[4];
    const float* Wc    = (const float*)d_in[5];
    float* Y = (float*)d_out;

    char* ws = (char*)d_ws;
    unsigned short* Q  = (unsigned short*)(ws);                      // 8 MB
    unsigned short* K  = (unsigned short*)(ws + ((size_t)8 << 20));  // 8 MB
    unsigned short* Vt = (unsigned short*)(ws + ((size_t)16 << 20)); // 8 MB
    unsigned short* O  = (unsigned short*)(ws + ((size_t)24 << 20)); // 8 MB

    qkv_kernel<<<(N_B * S_LEN / 32) * 3, 256, 0, stream>>>(x, theta, Wq, Wk, Wv, Q, K, Vt);
    flash_kernel<<<N_B * N_H * (S_LEN / 128), 512, 0, stream>>>(Q, K, Vt, O);
    outproj_kernel<<<(N_B * S_LEN / 64) * (E_DIM / 128), 512, 0, stream>>>(O, Wc, Y);
}

// Round 10
// 136.306 us; speedup vs baseline: 1.0259x; 1.0259x over previous
//
#include <hip/hip_runtime.h>
#include <stdint.h>

#define N_B 4
#define S_LEN 2048
#define N_H 8
#define E_DIM 512

typedef __attribute__((ext_vector_type(8))) short bf16x8;
typedef __attribute__((ext_vector_type(4))) float f32x4;
typedef __attribute__((ext_vector_type(4))) unsigned int u32x4;
typedef __attribute__((ext_vector_type(2))) unsigned int u32x2;
typedef __attribute__((ext_vector_type(4))) unsigned short u16x4;
typedef __attribute__((ext_vector_type(8))) unsigned short u16x8;

#define MFMA16(a, b, c) __builtin_amdgcn_mfma_f32_16x16x32_bf16((a), (b), (c), 0, 0, 0)

__device__ __forceinline__ unsigned short f2bf(float f) {
    union { float f; unsigned int u; } v; v.f = f;
    unsigned int r = v.u + 0x7fffu + ((v.u >> 16) & 1u);
    return (unsigned short)(r >> 16);
}

// pack two f32 -> two bf16 (round-half-up) in one u32 via v_perm
__device__ __forceinline__ unsigned int pack2bf(float lo, float hi) {
    union { float f; unsigned int u; } a, b; a.f = lo; b.f = hi;
    return __builtin_amdgcn_perm(b.u + 0x8000u, a.u + 0x8000u, 0x07060302u);
}

__device__ __forceinline__ float fexp2(float x) {
#if __has_builtin(__builtin_amdgcn_exp2f)
    return __builtin_amdgcn_exp2f(x);
#else
    return exp2f(x);
#endif
}

// ---------------------------------------------------------------------------
// In-register quad redistribution (lane^32 and lane^16 swaps at fixed lq).
// ---------------------------------------------------------------------------
#if __has_builtin(__builtin_amdgcn_permlane32_swap) && __has_builtin(__builtin_amdgcn_permlane16_swap)
#define HAVE_PERMLANE_SWAP 1
#endif

__device__ __forceinline__ void pl32(unsigned int& x, unsigned int& y) {
#ifdef HAVE_PERMLANE_SWAP
    auto r = __builtin_amdgcn_permlane32_swap(x, y, false, false);
    x = (unsigned int)r[0]; y = (unsigned int)r[1];
#else
    const int idx = (((int)threadIdx.x & 63) ^ 32) << 2;
    unsigned int xs = (unsigned int)__builtin_amdgcn_ds_bpermute(idx, (int)x);
    unsigned int ys = (unsigned int)__builtin_amdgcn_ds_bpermute(idx, (int)y);
    const bool lo = (threadIdx.x & 32) == 0;
    unsigned int nx = lo ? x : ys;
    unsigned int ny = lo ? xs : y;
    x = nx; y = ny;
#endif
}

__device__ __forceinline__ void pl16(unsigned int& x, unsigned int& y) {
#ifdef HAVE_PERMLANE_SWAP
    auto r = __builtin_amdgcn_permlane16_swap(x, y, false, false);
    x = (unsigned int)r[0]; y = (unsigned int)r[1];
#else
    unsigned int zs = (unsigned int)__builtin_amdgcn_ds_swizzle((int)y, 0x401F); // y[lane^16]
    unsigned int ws = (unsigned int)__builtin_amdgcn_ds_swizzle((int)x, 0x401F); // x[lane^16]
    const bool evenq = (threadIdx.x & 16) == 0;
    unsigned int nx = evenq ? x : zs;
    unsigned int ny = evenq ? ws : y;
    x = nx; y = ny;
#endif
}

// Q pre-scale: 1/sqrt(64) * log2(e)
#define Q_SCALE 0.18033688f

// ---------------------------------------------------------------------------
// Kernel 1: proj = cos(x+theta); Q,K row-major [BH][S][64] bf16 (Q*Q_SCALE);
//           Vt [BH][64][S] bf16.  grid = 256 chunks x 3 mats = 768 blocks.
// (R3-verified, byte-identical.)
// ---------------------------------------------------------------------------
__global__ __launch_bounds__(256) void qkv_kernel(
    const float* __restrict__ x, const float* __restrict__ theta,
    const float* __restrict__ Wq, const float* __restrict__ Wk,
    const float* __restrict__ Wv,
    unsigned short* __restrict__ Q, unsigned short* __restrict__ K,
    unsigned short* __restrict__ Vt)
{
    __shared__ float proj[32][8];
    const int tid = threadIdx.x;
    const int mat = blockIdx.x % 3;
    const int chunk = blockIdx.x / 3;
    const int row0 = chunk * 32;
    const int b = row0 >> 11;
    const int s_in_b = row0 & (S_LEN - 1);

    proj[tid >> 3][tid & 7] = cosf(x[row0 * 8 + tid] + theta[tid & 7]);
    __syncthreads();

    if (mat < 2) {
        const float* W = (mat == 0) ? Wq : Wk;
        const float scale = (mat == 0) ? Q_SCALE : 1.0f;
        unsigned short* outp = (mat == 0) ? Q : K;
        const int eg = (tid & 127) * 4;      // 4 consecutive e-columns
        const int sg = (tid >> 7) * 16;      // 16 s-rows
        float w[4][8];
        #pragma unroll
        for (int e = 0; e < 4; ++e)
            #pragma unroll
            for (int n = 0; n < 8; ++n)
                w[e][n] = W[(eg + e) * 8 + n] * scale;
        const int h = eg >> 6, d0 = eg & 63;
        unsigned short* p0 = outp + ((size_t)(b * N_H + h) * S_LEN + s_in_b + sg) * 64 + d0;
        #pragma unroll 4
        for (int s = 0; s < 16; ++s) {
            f32x4 pa = *(const f32x4*)&proj[sg + s][0];
            f32x4 pc = *(const f32x4*)&proj[sg + s][4];
            u16x4 o;
            #pragma unroll
            for (int e = 0; e < 4; ++e) {
                float a = 0.f;
                #pragma unroll
                for (int n = 0; n < 4; ++n)
                    a += pa[n] * w[e][n] + pc[n] * w[e][n + 4];
                o[e] = f2bf(a);
            }
            *(u16x4*)&p0[s * 64] = o;
        }
    } else {
        // Vt: 4 lanes per e-column; lane handles 8 s-values -> u16x8.
        f32x4 ps[8][2];
        const int sl0 = (tid & 3) * 8;
        #pragma unroll
        for (int k2 = 0; k2 < 8; ++k2) {
            ps[k2][0] = *(const f32x4*)&proj[sl0 + k2][0];
            ps[k2][1] = *(const f32x4*)&proj[sl0 + k2][4];
        }
        const int ecol = tid >> 2;   // 0..63
        for (int pass = 0; pass < 8; ++pass) {
            const int e = pass * 64 + ecol;
            const int h = e >> 6, dd = e & 63;
            float wr[8];
            #pragma unroll
            for (int n = 0; n < 8; ++n) wr[n] = Wv[e * 8 + n];
            u16x8 pk;
            #pragma unroll
            for (int k2 = 0; k2 < 8; ++k2) {
                float acc = 0.f;
                #pragma unroll
                for (int n = 0; n < 4; ++n)
                    acc += ps[k2][0][n] * wr[n] + ps[k2][1][n] * wr[n + 4];
                pk[k2] = f2bf(acc);
            }
            *(u16x8*)&Vt[((size_t)(b * N_H + h) * 64 + dd) * S_LEN + s_in_b + sl0] = pk;
        }
    }
}

// ---------------------------------------------------------------------------
// Kernel 2: flash attention, fixed-max (M=0) softmax, IN-BLOCK K-SPLIT x2.
// (R3-verified 52.9us, byte-identical. Best measured config: no lsacc-MFMA,
// no setprio — R9 showed both lengthen the serial QK->exp2->permlane->PV
// dependency chain, which is the binding constraint at this structure.)
// ---------------------------------------------------------------------------
__global__ __launch_bounds__(512, 4) void flash_kernel(
    const unsigned short* __restrict__ Q, const unsigned short* __restrict__ K,
    const unsigned short* __restrict__ Vt, unsigned short* __restrict__ O)
{
    __shared__ short kt[2][2][64 * 72];   // [group][dbuf][k=64][d=64+pad]
    __shared__ short vt[2][2][64 * 72];   // [group][dbuf][d=64][s=64+pad]

    const int tid = threadIdx.x;               // 0..511
    const int lane = tid & 63, w = tid >> 6;   // w 0..7
    const int g = tid >> 8;                    // k-split group
    const int wq = w & 3;                      // q-wave within group
    const int tg = tid & 255;                  // thread within group
    const int quad = lane >> 4, lq = lane & 15;
    // bijective XCD swizzle (512 blocks, 8 XCDs)
    const int bid = ((int)blockIdx.x & 7) * 64 + ((int)blockIdx.x >> 3);
    const int qt = bid & 15, bh = bid >> 4;
    const int b = bh >> 3, h = bh & 7;

    const unsigned short* Qb = Q + (size_t)bh * S_LEN * 64;
    const unsigned short* Kb = K + (size_t)bh * S_LEN * 64;
    const unsigned short* Vb = Vt + (size_t)bh * 64 * S_LEN;
    const int kbase = g * 1024;                // this group's k-range start

    // Q fragments (MFMA B-operand): lane holds Q[q=lq][d=quad*8+j]
    bf16x8 qf[2][2];
    #pragma unroll
    for (int mt = 0; mt < 2; ++mt)
        #pragma unroll
        for (int ks = 0; ks < 2; ++ks)
            qf[mt][ks] = *(const bf16x8*)&Qb[(size_t)(qt * 128 + wq * 32 + mt * 16 + lq) * 64 + ks * 32 + quad * 8];

    f32x4 oacc[2][4];
    #pragma unroll
    for (int mt = 0; mt < 2; ++mt)
        #pragma unroll
        for (int dt = 0; dt < 4; ++dt) oacc[mt][dt] = 0.f;
    float lsum[2] = {0.f, 0.f};

    // prologue: group tile 0 -> regs -> buf0; group tile 1 -> regs (in flight)
    u32x4 pkr[2], pvr[2];
    #pragma unroll
    for (int i = 0; i < 2; ++i) {
        const int u = tg + (i << 8);
        pkr[i] = *(const u32x4*)&Kb[(size_t)(kbase + (u >> 3)) * 64 + (u & 7) * 8];
        pvr[i] = *(const u32x4*)&Vb[(size_t)(u >> 3) * S_LEN + kbase + (u & 7) * 8];
    }
    #pragma unroll
    for (int i = 0; i < 2; ++i) {
        const int u = tg + (i << 8);
        *(u32x4*)&kt[g][0][(u >> 3) * 72 + (u & 7) * 8] = pkr[i];
        *(u32x4*)&vt[g][0][(u >> 3) * 72 + (u & 7) * 8] = pvr[i];
    }
    #pragma unroll
    for (int i = 0; i < 2; ++i) {
        const int u = tg + (i << 8);
        pkr[i] = *(const u32x4*)&Kb[(size_t)(kbase + 64 + (u >> 3)) * 64 + (u & 7) * 8];
        pvr[i] = *(const u32x4*)&Vb[(size_t)(u >> 3) * S_LEN + kbase + 64 + (u & 7) * 8];
    }
    asm volatile("s_waitcnt lgkmcnt(0)" ::: "memory");
    __builtin_amdgcn_s_barrier();

    for (int kti = 0; kti < 16; ++kti) {
        const int cur = kti & 1, nxt = cur ^ 1;

        // stage group tile kti+1 (regs) -> buf[nxt] (counted vmcnt emitted here)
        #pragma unroll
        for (int i = 0; i < 2; ++i) {
            const int u = tg + (i << 8);
            *(u32x4*)&kt[g][nxt][(u >> 3) * 72 + (u & 7) * 8] = pkr[i];
            *(u32x4*)&vt[g][nxt][(u >> 3) * 72 + (u & 7) * 8] = pvr[i];
        }
        // prefetch group tile kti+2 -> regs (dummy tile 0 past end)
        const int kb2 = kbase + ((kti < 14) ? (kti + 2) * 64 : 0);
        #pragma unroll
        for (int i = 0; i < 2; ++i) {
            const int u = tg + (i << 8);
            pkr[i] = *(const u32x4*)&Kb[(size_t)(kb2 + (u >> 3)) * 64 + (u & 7) * 8];
            pvr[i] = *(const u32x4*)&Vb[(size_t)(u >> 3) * S_LEN + kb2 + (u & 7) * 8];
        }

        const short* ktc = &kt[g][cur][0];
        const short* vtc = &vt[g][cur][0];

        // S^T = K . Q^T : lane (quad,lq) elem r -> S^T[k=mts*16+quad*4+r][q=lq]
        f32x4 sacc[2][4];
        #pragma unroll
        for (int mt = 0; mt < 2; ++mt)
            #pragma unroll
            for (int mts = 0; mts < 4; ++mts) sacc[mt][mts] = 0.f;
        #pragma unroll
        for (int mts = 0; mts < 4; ++mts) {
            #pragma unroll
            for (int ks = 0; ks < 2; ++ks) {
                bf16x8 af = *(const bf16x8*)&ktc[(mts * 16 + lq) * 72 + ks * 32 + quad * 8];
                sacc[0][mts] = MFMA16(af, qf[0][ks], sacc[0][mts]);
                sacc[1][mts] = MFMA16(af, qf[1][ks], sacc[1][mts]);
            }
        }

        // fixed-max softmax + in-register transpose S^T -> PV A-fragments
        unsigned int afr[2][2][4];
        #pragma unroll
        for (int mt = 0; mt < 2; ++mt) {
            unsigned int u_[4][2];
            #pragma unroll
            for (int mts = 0; mts < 4; ++mts) {
                f32x4 p;
                #pragma unroll
                for (int e = 0; e < 4; ++e) p[e] = fexp2(sacc[mt][mts][e]);
                lsum[mt] += (p[0] + p[1]) + (p[2] + p[3]);
                u_[mts][0] = pack2bf(p[0], p[1]);
                u_[mts][1] = pack2bf(p[2], p[3]);
            }
            #pragma unroll
            for (int ks = 0; ks < 2; ++ks) {
                #pragma unroll
                for (int wd = 0; wd < 2; ++wd) {
                    unsigned int a = u_[ks * 2][wd];
                    unsigned int c = u_[ks * 2 + 1][wd];
                    pl32(a, c);
                    pl16(a, c);
                    afr[mt][ks][wd] = a;
                    afr[mt][ks][2 + wd] = c;
                }
            }
        }

        // O += P . V
        #pragma unroll
        for (int ks = 0; ks < 2; ++ks) {
            union { unsigned int u[4]; bf16x8 v; } a0, a1;
            #pragma unroll
            for (int j = 0; j < 4; ++j) { a0.u[j] = afr[0][ks][j]; a1.u[j] = afr[1][ks][j]; }
            #pragma unroll
            for (int dt = 0; dt < 4; ++dt) {
                bf16x8 bf = *(const bf16x8*)&vtc[(dt * 16 + lq) * 72 + ks * 32 + quad * 8];
                oacc[0][dt] = MFMA16(a0.v, bf, oacc[0][dt]);
                oacc[1][dt] = MFMA16(a1.v, bf, oacc[1][dt]);
            }
        }

        asm volatile("s_waitcnt lgkmcnt(0)" ::: "memory");
        __builtin_amdgcn_s_barrier();
    }

    // ---- k-split combine: group 1 -> LDS -> group 0 adds (pure f32) ----
    float* exO = (float*)&kt[0][0][0];   // stride-36 layout, 36844 B <= 36864
    float* exL = (float*)&vt[0][0][0];
    const int fb = wq * 2304 + lane * 36;
    if (g == 1) {
        #pragma unroll
        for (int mt = 0; mt < 2; ++mt)
            #pragma unroll
            for (int dt = 0; dt < 4; ++dt)
                *(f32x4*)&exO[fb + (mt * 4 + dt) * 4] = oacc[mt][dt];
        exL[(wq * 64 + lane) * 2 + 0] = lsum[0];
        exL[(wq * 64 + lane) * 2 + 1] = lsum[1];
    }
    __syncthreads();
    if (g == 0) {
        #pragma unroll
        for (int mt = 0; mt < 2; ++mt)
            #pragma unroll
            for (int dt = 0; dt < 4; ++dt)
                oacc[mt][dt] += *(const f32x4*)&exO[fb + (mt * 4 + dt) * 4];
        lsum[0] += exL[(wq * 64 + lane) * 2 + 0];
        lsum[1] += exL[(wq * 64 + lane) * 2 + 1];

        // epilogue: reduce row-sums across quads, normalize, store O
        #pragma unroll
        for (int mt = 0; mt < 2; ++mt) {
            float rs = lsum[mt];
            rs += __shfl_xor(rs, 16);
            rs += __shfl_xor(rs, 32);
            const float inv = 1.0f / rs;
            #pragma unroll
            for (int r = 0; r < 4; ++r) {
                const float ir = __shfl(inv, quad * 4 + r);
                const int row = qt * 128 + wq * 32 + mt * 16 + quad * 4 + r;
                unsigned short* dst = &O[((size_t)b * S_LEN + row) * E_DIM + h * 64];
                #pragma unroll
                for (int dt = 0; dt < 4; ++dt)
                    dst[dt * 16 + lq] = f2bf(oacc[mt][dt][r] * ir);
            }
        }
    }
}

// ---------------------------------------------------------------------------
// Kernel 3: Y[m][f] = sum_e O[m][e]*Wc[f][e]. 64x64 tiles -> 1024 blocks
// (4 blocks/CU). Register prefetch of next K-chunk. (R3-verified,
// byte-identical; R8's BM64xBN128 retile measured equal within noise —
// O+Wc fit L3 so the traffic reduction was already absorbed by cache.)
// ---------------------------------------------------------------------------
__global__ __launch_bounds__(256, 4) void outproj_kernel(
    const unsigned short* __restrict__ O, const float* __restrict__ Wc,
    float* __restrict__ Y)
{
    __shared__ short at[64 * 72];
    __shared__ short bt[64 * 72];
    const int tid = threadIdx.x;
    const int lane = tid & 63, w = tid >> 6;
    const int quad = lane >> 4, lq = lane & 15;
    const int m0 = (blockIdx.x >> 3) * 64;
    const int f0 = (blockIdx.x & 7) * 64;

    f32x4 acc[4];
    #pragma unroll
    for (int nt = 0; nt < 4; ++nt) acc[nt] = 0.f;

    // preload chunk 0
    u32x4 pa[2];
    f32x4 pw[4];
    #pragma unroll
    for (int i = 0; i < 2; ++i) {
        const int u = tid + (i << 8);
        pa[i] = *(const u32x4*)&O[(size_t)(m0 + (u >> 3)) * E_DIM + (u & 7) * 8];
    }
    #pragma unroll
    for (int i = 0; i < 4; ++i) {
        const int u = tid + (i << 8);
        pw[i] = *(const f32x4*)&Wc[(size_t)(f0 + (u >> 4)) * E_DIM + (u & 15) * 4];
    }

    for (int e0 = 0; e0 < E_DIM; e0 += 64) {
        __syncthreads();
        #pragma unroll
        for (int i = 0; i < 2; ++i) {
            const int u = tid + (i << 8);
            *(u32x4*)&at[(u >> 3) * 72 + (u & 7) * 8] = pa[i];
        }
        #pragma unroll
        for (int i = 0; i < 4; ++i) {
            const int u = tid + (i << 8);
            u16x4 pk = { f2bf(pw[i][0]), f2bf(pw[i][1]), f2bf(pw[i][2]), f2bf(pw[i][3]) };
            *(u16x4*)&bt[(u >> 4) * 72 + (u & 15) * 4] = pk;
        }
        __syncthreads();

        const int e1 = (e0 + 64 < E_DIM) ? e0 + 64 : 0;
        #pragma unroll
        for (int i = 0; i < 2; ++i) {
            const int u = tid + (i << 8);
            pa[i] = *(const u32x4*)&O[(size_t)(m0 + (u >> 3)) * E_DIM + e1 + (u & 7) * 8];
        }
        #pragma unroll
        for (int i = 0; i < 4; ++i) {
            const int u = tid + (i << 8);
            pw[i] = *(const f32x4*)&Wc[(size_t)(f0 + (u >> 4)) * E_DIM + e1 + (u & 15) * 4];
        }

        bf16x8 afk[2];
        #pragma unroll
        for (int ks = 0; ks < 2; ++ks)
            afk[ks] = *(const bf16x8*)&at[(w * 16 + lq) * 72 + ks * 32 + quad * 8];
        #pragma unroll
        for (int nt = 0; nt < 4; ++nt) {
            #pragma unroll
            for (int ks = 0; ks < 2; ++ks) {
                bf16x8 bf = *(const bf16x8*)&bt[(nt * 16 + lq) * 72 + ks * 32 + quad * 8];
                acc[nt] = MFMA16(afk[ks], bf, acc[nt]);
            }
        }
    }

    #pragma unroll
    for (int nt = 0; nt < 4; ++nt)
        #pragma unroll
        for (int r = 0; r < 4; ++r)
            Y[(size_t)(m0 + w * 16 + quad * 4 + r) * E_DIM + f0 + nt * 16 + lq] = acc[nt][r];
}

// ---------------------------------------------------------------------------
extern "C" void kernel_launch(void* const* d_in, const int* in_sizes, int n_in,
                              void* d_out, int out_size, void* d_ws, size_t ws_size,
                              hipStream_t stream) {
    const float* x     = (const float*)d_in[0];
    const float* theta = (const float*)d_in[1];
    const float* Wq    = (const float*)d_in[2];
    const float* Wk    = (const float*)d_in[3];
    const float* Wv    = (const float*)d_in[4];
    const float* Wc    = (const float*)d_in[5];
    float* Y = (float*)d_out;

    char* ws = (char*)d_ws;
    unsigned short* Q  = (unsigned short*)(ws);                      // 8 MB
    unsigned short* K  = (unsigned short*)(ws + ((size_t)8 << 20));  // 8 MB
    unsigned short* Vt = (unsigned short*)(ws + ((size_t)16 << 20)); // 8 MB
    unsigned short* O  = (unsigned short*)(ws + ((size_t)24 << 20)); // 8 MB

    qkv_kernel<<<(N_B * S_LEN / 32) * 3, 256, 0, stream>>>(x, theta, Wq, Wk, Wv, Q, K, Vt);
    flash_kernel<<<N_B * N_H * (S_LEN / 128), 512, 0, stream>>>(Q, K, Vt, O);
    outproj_kernel<<<(N_B * S_LEN / 64) * (E_DIM / 64), 256, 0, stream>>>(O, Wc, Y);
}